// Round 5
// baseline (272.085 us; speedup 1.0000x reference)
//
#include <hip/hip_runtime.h>
#include <stdint.h>

#define HIDDEN 1024
#define HEADS 16
#define HEAD_DIM 64
#define BATCH 4
#define SEQ 2048
#define ROWS (BATCH * SEQ) /* 8192 */

typedef float f32x4 __attribute__((ext_vector_type(4)));
typedef short bf16x8 __attribute__((ext_vector_type(8))); // 8 bf16 = 4 VGPRs

__device__ __forceinline__ uint16_t f32_to_bf16_rne(float f) {
    uint32_t u = __float_as_uint(f);
    uint32_t r = u + 0x7FFFu + ((u >> 16) & 1u);
    return (uint16_t)(r >> 16);
}
__device__ __forceinline__ float bf16_to_f32(uint16_t u) {
    return __uint_as_float(((uint32_t)u) << 16);
}

// ---------------------------------------------------------------------------
// Kernel 0: convert X (q,k,v inputs) fp32 -> bf16, fully coalesced.
// ---------------------------------------------------------------------------
__global__ __launch_bounds__(256) void cvt_kernel(const float* __restrict__ Xq,
                                                  const float* __restrict__ Xk,
                                                  const float* __restrict__ Xv,
                                                  uint16_t* __restrict__ Xb) {
    int z = blockIdx.x >> 13; // 8192 blocks per array
    const float* X = z == 0 ? Xq : (z == 1 ? Xk : Xv);
    uint16_t* out = Xb + (size_t)z * ROWS * HIDDEN;
    size_t i4 = (size_t)(blockIdx.x & 8191) * 256 + threadIdx.x; // float4 index
    float4 f = ((const float4*)X)[i4];
    uint2 pk;
    pk.x = (uint32_t)f32_to_bf16_rne(f.x) | ((uint32_t)f32_to_bf16_rne(f.y) << 16);
    pk.y = (uint32_t)f32_to_bf16_rne(f.z) | ((uint32_t)f32_to_bf16_rne(f.w) << 16);
    ((uint2*)out)[i4] = pk;
}

// ---------------------------------------------------------------------------
// Kernel 1: W[K][N] fp32 -> Wt[N][K] bf16, z in {Wk, Wv} only (Wq stays fp32)
// ---------------------------------------------------------------------------
__global__ __launch_bounds__(256) void wt_kernel(const float* __restrict__ Wk,
                                                 const float* __restrict__ Wv,
                                                 uint16_t* __restrict__ Wt) {
    const float* W = blockIdx.z == 0 ? Wk : Wv;
    uint16_t* out = Wt + (size_t)blockIdx.z * HIDDEN * HIDDEN;
    __shared__ float tile[64][65];
    int k0 = blockIdx.x * 64, n0 = blockIdx.y * 64;
    int r = threadIdx.x >> 6, c = threadIdx.x & 63;
    for (int it = 0; it < 16; ++it) {
        int rr = r + 4 * it;
        tile[rr][c] = W[(size_t)(k0 + rr) * HIDDEN + n0 + c];
    }
    __syncthreads();
    for (int it = 0; it < 16; ++it) {
        int rr = r + 4 * it;
        out[(size_t)(n0 + rr) * HIDDEN + k0 + c] = f32_to_bf16_rne(tile[c][rr]);
    }
}

// ---------------------------------------------------------------------------
// Kernel 2a: K projection (z=0) — 256x128 tile, BK=64, 8 waves (4Mx2N),
//   8-phase counted-vmcnt schedule. Per-wave output 64x64 -> acc[4][4] = 64
//   regs (HALF of the failed 256^2 ports: rounds 1-3 spilled with acc=128).
//   LDS 96 KiB: 2 x (A 256x64 + B 128x64) bf16. Chunk-XOR swizzle (0 conflicts).
//   WAR safety: each LDS region is restaged only after the barrier following
//   its last read phase (B read ph1/ph2 -> staged ph3; A read ph1-ph3 ->
//   staged ph5/ph6). vmcnt(2) at ph4/ph8 = newest STAGE (2 loads) in flight.
// ---------------------------------------------------------------------------

// Stage one 128-row x 64-col bf16 half-tile: 512 thr x 2 x 16B gload_lds.
#define KSTAGE(GSRC, CHUNKBASE)                                                  \
    {                                                                            \
        _Pragma("unroll") for (int l = 0; l < 2; ++l) {                          \
            int gb = l * 512 + w * 64; /* wave-uniform chunk base */             \
            int g = gb + lane;                                                   \
            int r = g >> 3;                                                      \
            int c = (g & 7) ^ (r & 7);                                           \
            __builtin_amdgcn_global_load_lds(                                    \
                (const __attribute__((address_space(1))) uint32_t*)((GSRC) +     \
                    (size_t)r * HIDDEN + c * 8),                                 \
                (__attribute__((address_space(3))) uint32_t*)(&lds[((CHUNKBASE) + gb) * 8]), \
                16, 0, 0);                                                       \
        }                                                                        \
    }

// A half (2 M-frags x 2 k-slices) from buf BUF, MH in {0,1}.
#define KLDA(BUF, MH)                                                            \
    {                                                                            \
        _Pragma("unroll") for (int fi = 0; fi < 2; ++fi) {                       \
            int ar = wm + ((MH) * 2 + fi) * 16 + m_lane;                         \
            _Pragma("unroll") for (int ks = 0; ks < 2; ++ks) {                   \
                int p = (ks * 4 + kq) ^ (ar & 7);                                \
                aq[fi][ks] = *(const bf16x8*)(&lds[(BUF) + ar * 64 + p * 8]);    \
            }                                                                    \
        }                                                                        \
    }

// B half (2 N-frags x 2 k-slices), NH in {0,1}, into BQ.
#define KLDB(BUF, NH, BQ)                                                        \
    {                                                                            \
        _Pragma("unroll") for (int fj = 0; fj < 2; ++fj) {                       \
            int br = wn + ((NH) * 2 + fj) * 16 + m_lane;                         \
            _Pragma("unroll") for (int ks = 0; ks < 2; ++ks) {                   \
                int p = (ks * 4 + kq) ^ (br & 7);                                \
                BQ[fj][ks] = *(const bf16x8*)(&lds[(BUF) + 16384 + br * 64 + p * 8]); \
            }                                                                    \
        }                                                                        \
    }

// 8 MFMA: one C-quadrant (2x2 frags) x K=64 (2 k-slices).
#define KMFMA(BQ, MH, NH)                                                        \
    {                                                                            \
        _Pragma("unroll") for (int ks = 0; ks < 2; ++ks)                         \
        _Pragma("unroll") for (int fi = 0; fi < 2; ++fi)                         \
        _Pragma("unroll") for (int fj = 0; fj < 2; ++fj)                         \
            acc[(MH) * 2 + fi][(NH) * 2 + fj] =                                  \
                __builtin_amdgcn_mfma_f32_16x16x32_bf16(                         \
                    aq[fi][ks], BQ[fj][ks], acc[(MH) * 2 + fi][(NH) * 2 + fj], 0, 0, 0); \
    }

#define KMID()                                                                   \
    __builtin_amdgcn_s_barrier();                                                \
    asm volatile("s_waitcnt lgkmcnt(0)" ::: "memory");                           \
    __builtin_amdgcn_s_setprio(1);

#define KEND()                                                                   \
    __builtin_amdgcn_s_setprio(0);                                               \
    __builtin_amdgcn_s_barrier();

// buf0: A chunks [0,2048), B chunks [2048,3072); buf1: +3072 chunks.
#define B0A 0
#define B0B 2048
#define B1A 3072
#define B1B 5120

__global__ __launch_bounds__(512, 1) void projk8(const uint16_t* __restrict__ X,
                                                 const uint16_t* __restrict__ W,
                                                 const float* __restrict__ bias,
                                                 uint16_t* __restrict__ out) {
    extern __shared__ uint16_t lds[]; // 98304 B

    const int tid = threadIdx.x;
    const int lane = tid & 63;
    const int w = tid >> 6;          // 8 waves
    const int wm = (w >> 1) * 64;    // 4 M-waves
    const int wn = (w & 1) * 64;     // 2 N-waves
    const int m_lane = lane & 15;
    const int kq = lane >> 4;
    const int m0 = blockIdx.x * 256;
    const int n0 = blockIdx.y * 128;

    const uint16_t* Xb = X + (size_t)m0 * HIDDEN;
    const uint16_t* Wb = W + (size_t)n0 * HIDDEN;

    f32x4 acc[4][4] = {};
    bf16x8 aq[2][2], b0q[2][2], b1q[2][2];

    // ---- prologue: T0 (A0,A1,B) + T1.B; wait T0 (newest 2 = T1.B) ----
    KSTAGE(Xb, B0A);                         // T0.A rows 0-127
    KSTAGE(Xb + 128 * HIDDEN, B0A + 1024);   // T0.A rows 128-255
    KSTAGE(Wb, B0B);                         // T0.B
    KSTAGE(Wb + 64, B1B);                    // T1.B
    asm volatile("s_waitcnt vmcnt(2)" ::: "memory");
    __builtin_amdgcn_s_barrier();

    // ---- main: 7 iters x 2 K-tiles (t0=2i buf0, t1=2i+1 buf1) ----
#pragma unroll 1
    for (int i = 0; i < 7; ++i) {
        const int kb = i * 128;
        // ph1: quad(0,0) tile t0; stage t1.A0 -> buf1.A
        KLDA(0, 0); KLDB(0, 0, b0q);
        KSTAGE(Xb + kb + 64, B1A);
        KMID(); KMFMA(b0q, 0, 0); KEND();
        // ph2: quad(0,1); stage t1.A1
        KLDB(0, 1, b1q);
        KSTAGE(Xb + 128 * HIDDEN + kb + 64, B1A + 1024);
        KMID(); KMFMA(b1q, 0, 1); KEND();
        // ph3: quad(1,1); stage t2.B -> buf0.B (last read ph2)
        KLDA(0, 1);
        KSTAGE(Wb + kb + 128, B0B);
        KMID(); KMFMA(b1q, 1, 1); KEND();
        // ph4: quad(1,0); counted vmcnt: t1 landed (newest 2 = t2.B)
        asm volatile("s_waitcnt vmcnt(2)" ::: "memory");
        __builtin_amdgcn_s_barrier();
        __builtin_amdgcn_s_setprio(1);
        KMFMA(b0q, 1, 0);
        KEND();
        // ph5: quad(0,0) tile t1; stage t2.A0 -> buf0.A (last read ph3)
        KLDA(24576, 0); KLDB(24576, 0, b0q);
        KSTAGE(Xb + kb + 128, B0A);
        KMID(); KMFMA(b0q, 0, 0); KEND();
        // ph6: quad(0,1); stage t2.A1
        KLDB(24576, 1, b1q);
        KSTAGE(Xb + 128 * HIDDEN + kb + 128, B0A + 1024);
        KMID(); KMFMA(b1q, 0, 1); KEND();
        // ph7: quad(1,1); stage t3.B -> buf1.B (last read ph6)
        KLDA(24576, 1);
        KSTAGE(Wb + kb + 192, B1B);
        KMID(); KMFMA(b1q, 1, 1); KEND();
        // ph8: quad(1,0); counted vmcnt: t2 landed (newest 2 = t3.B)
        asm volatile("s_waitcnt vmcnt(2)" ::: "memory");
        __builtin_amdgcn_s_barrier();
        __builtin_amdgcn_s_setprio(1);
        KMFMA(b0q, 1, 0);
        KEND();
    }

    // ---- epilogue: tiles 14 [buf0], 15 [buf1]; stage only t15.A ----
    {
        const int kb = 896;
        KLDA(0, 0); KLDB(0, 0, b0q);
        KSTAGE(Xb + kb + 64, B1A);
        KMID(); KMFMA(b0q, 0, 0); KEND();
        KLDB(0, 1, b1q);
        KSTAGE(Xb + 128 * HIDDEN + kb + 64, B1A + 1024);
        KMID(); KMFMA(b1q, 0, 1); KEND();
        KLDA(0, 1);
        KMID(); KMFMA(b1q, 1, 1); KEND();
        asm volatile("s_waitcnt vmcnt(0)" ::: "memory");
        __builtin_amdgcn_s_barrier();
        __builtin_amdgcn_s_setprio(1);
        KMFMA(b0q, 1, 0);
        KEND();
        KLDA(24576, 0); KLDB(24576, 0, b0q);
        KMID(); KMFMA(b0q, 0, 0); KEND();
        KLDB(24576, 1, b1q);
        KMID(); KMFMA(b1q, 0, 1); KEND();
        KLDA(24576, 1);
        KMID(); KMFMA(b1q, 1, 1); KEND();
        __builtin_amdgcn_s_setprio(1);
        KMFMA(b0q, 1, 0);
        __builtin_amdgcn_s_setprio(0);
    }

    // ---- C write: per wave 64x64, verified C/D mapping ----
    for (int fj = 0; fj < 4; ++fj) {
        int col = n0 + wn + fj * 16 + m_lane;
        float bj = bias[col];
        for (int fi = 0; fi < 4; ++fi) {
            int rbase = m0 + wm + fi * 16 + kq * 4;
            for (int rg = 0; rg < 4; ++rg) {
                float v = acc[fi][fj][rg] + bj;
                out[(size_t)(rbase + rg) * HIDDEN + col] = f32_to_bf16_rne(v);
            }
        }
    }
}

// ---------------------------------------------------------------------------
// Kernel 2b: V projection — round-0 verified m97 128x128 structure.
// ---------------------------------------------------------------------------
__global__ __launch_bounds__(256) void proj_gemm(const uint16_t* __restrict__ Xkv,
                                                 const uint16_t* __restrict__ Wt,
                                                 const float* __restrict__ Bk,
                                                 const float* __restrict__ Bv,
                                                 uint16_t* __restrict__ KV) {
    const int z = blockIdx.z;
    const uint16_t* X = Xkv + (size_t)z * ROWS * HIDDEN;
    const uint16_t* W = Wt + (size_t)z * HIDDEN * HIDDEN;
    const float* bias = z == 0 ? Bk : Bv;
    uint16_t* out = KV + (size_t)z * ROWS * HIDDEN;

    __shared__ uint16_t slds[16384]; // A: [0,8192), B: [8192,16384)

    const int tid = threadIdx.x;
    const int lane = tid & 63;
    const int w = tid >> 6;
    const int wm = (w >> 1) * 64;
    const int wn = (w & 1) * 64;
    const int m_lane = lane & 15;
    const int kq = lane >> 4;
    const int m0 = blockIdx.x * 128;
    const int n0 = blockIdx.y * 128;

    f32x4 acc[4][4] = {};

    for (int kb = 0; kb < HIDDEN; kb += 64) {
        for (int t = 0; t < 4; ++t) {
            int gbase = (w * 4 + t) * 64;
            int g = gbase + lane;
            int r = g >> 3;
            int c = (g & 7) ^ (r & 7);
            const uint16_t* srcA = X + (size_t)(m0 + r) * HIDDEN + kb + c * 8;
            __builtin_amdgcn_global_load_lds(
                (const __attribute__((address_space(1))) uint32_t*)srcA,
                (__attribute__((address_space(3))) uint32_t*)(&slds[gbase * 8]),
                16, 0, 0);
            const uint16_t* srcB = W + (size_t)(n0 + r) * HIDDEN + kb + c * 8;
            __builtin_amdgcn_global_load_lds(
                (const __attribute__((address_space(1))) uint32_t*)srcB,
                (__attribute__((address_space(3))) uint32_t*)(&slds[8192 + gbase * 8]),
                16, 0, 0);
        }
        __syncthreads();
        for (int ks = 0; ks < 2; ++ks) {
            int cbase = ks * 4 + kq;
            bf16x8 af[4], bfr[4];
            for (int i = 0; i < 4; ++i) {
                int r = wm + i * 16 + m_lane;
                int p = cbase ^ (r & 7);
                af[i] = *(const bf16x8*)(&slds[r * 64 + p * 8]);
            }
            for (int j = 0; j < 4; ++j) {
                int nr = wn + j * 16 + m_lane;
                int p = cbase ^ (nr & 7);
                bfr[j] = *(const bf16x8*)(&slds[8192 + nr * 64 + p * 8]);
            }
            for (int i = 0; i < 4; ++i)
                for (int j = 0; j < 4; ++j)
                    acc[i][j] = __builtin_amdgcn_mfma_f32_16x16x32_bf16(
                        af[i], bfr[j], acc[i][j], 0, 0, 0);
        }
        __syncthreads();
    }

    for (int j = 0; j < 4; ++j) {
        int col = n0 + wn + j * 16 + m_lane;
        float bj = bias[col];
        for (int i = 0; i < 4; ++i) {
            int rbase = m0 + wm + i * 16 + kq * 4;
            for (int rg = 0; rg < 4; ++rg) {
                float v = acc[i][j][rg] + bj;
                out[(size_t)(rbase + rg) * HIDDEN + col] = f32_to_bf16_rne(v);
            }
        }
    }
}

// ---------------------------------------------------------------------------
// Kernel 3: P[bh][sc] = (1/8) * K_h^T V_h over a 256-row S chunk.
// ---------------------------------------------------------------------------
__global__ __launch_bounds__(256) void kv_kernel(const uint16_t* __restrict__ KV,
                                                 float* __restrict__ P) {
    const uint16_t* K = KV;
    const uint16_t* V = KV + (size_t)ROWS * HIDDEN;
    const int bh = blockIdx.x;  // b*16+h
    const int sc = blockIdx.y;  // 0..7, 256 rows each
    const int b = bh >> 4, h = bh & 15;
    const int tid = threadIdx.x;
    const size_t base = ((size_t)b * SEQ + sc * 256) * HIDDEN + h * 64;

    __shared__ float kk[16][64];
    __shared__ float vv[16][64];
    float acc[4][4] = {};
    const int i0 = (tid >> 4) * 4, j0 = (tid & 15) * 4;

    for (int batch = 0; batch < 16; ++batch) {
        __syncthreads();
        {
            int t = tid & 127;
            int row = t >> 3, c = t & 7;
            const uint16_t* src =
                (tid < 128 ? K : V) + base + (size_t)(batch * 16 + row) * HIDDEN + c * 8;
            float* dst = (tid < 128 ? &kk[row][c * 8] : &vv[row][c * 8]);
            bf16x8 d = *(const bf16x8*)src;
            for (int e = 0; e < 8; ++e) dst[e] = bf16_to_f32((uint16_t)d[e]);
        }
        __syncthreads();
        for (int r = 0; r < 16; ++r) {
            f32x4 ka = *(const f32x4*)(&kk[r][i0]);
            f32x4 va = *(const f32x4*)(&vv[r][j0]);
            for (int a = 0; a < 4; ++a)
                for (int bb = 0; bb < 4; ++bb)
                    acc[a][bb] += ka[a] * va[bb];
        }
    }
    float* Pp = P + ((size_t)bh * 8 + sc) * 4096;
    for (int a = 0; a < 4; ++a) {
        f32x4 row;
        for (int bb = 0; bb < 4; ++bb) row[bb] = acc[a][bb] * 0.125f;
        *(f32x4*)(&Pp[(i0 + a) * 64 + j0]) = row;
    }
}

// ---------------------------------------------------------------------------
// Kernel 4: fold M into weights — PER BATCH. Sums the 8 kv partials inline.
// ---------------------------------------------------------------------------
__global__ __launch_bounds__(256) void wprime_kernel(const float* __restrict__ Wq,
                                                     const float* __restrict__ bq,
                                                     const float* __restrict__ P,
                                                     uint16_t* __restrict__ Wpt,
                                                     float* __restrict__ bp) {
    const int h = blockIdx.x;
    const int r0 = blockIdx.y * 64;
    const int b = blockIdx.z;
    const int tid = threadIdx.x;

    __shared__ float Mh[64][65];
    __shared__ float Wl[64][65];
    const float* Pp = P + ((size_t)(b * 16 + h)) * 8 * 4096;
    for (int it = 0; it < 16; ++it) {
        int e = it * 256 + tid;
        int a = e >> 6, c = e & 63;
        float s = 0.f;
        for (int sc = 0; sc < 8; ++sc) s += Pp[sc * 4096 + e];
        Mh[a][c] = s;
        Wl[a][c] = Wq[(size_t)(r0 + a) * HIDDEN + h * 64 + c];
    }
    __syncthreads();

    const int r = tid & 63;
    const int jbase = tid >> 6; // 0..3
    float acc[16] = {};
    for (int i = 0; i < 64; ++i) {
        float wv = Wl[r][i];
        for (int jj = 0; jj < 16; ++jj)
            acc[jj] += wv * Mh[i][jbase + 4 * jj];
    }
    uint16_t* Wb = Wpt + (size_t)b * HIDDEN * HIDDEN;
    for (int jj = 0; jj < 16; ++jj) {
        int n = h * 64 + jbase + 4 * jj;
        Wb[(size_t)n * HIDDEN + r0 + r] = f32_to_bf16_rne(acc[jj]);
    }

    if (blockIdx.y == 0 && tid < 64) {
        int j = tid;
        float s = 0.f;
        for (int i = 0; i < 64; ++i) s += bq[h * 64 + i] * Mh[i][j];
        bp[b * HIDDEN + h * 64 + j] = s;
    }
}

// ---------------------------------------------------------------------------
// Kernel 5: out = Xq @ W'_b^T + b'_b   (fp32 output to d_out)
// ---------------------------------------------------------------------------
__global__ __launch_bounds__(256) void final_gemm(const uint16_t* __restrict__ Xq,
                                                  const uint16_t* __restrict__ Wpt,
                                                  const float* __restrict__ bp,
                                                  float* __restrict__ out) {
    __shared__ uint16_t slds[16384];

    const int tid = threadIdx.x;
    const int lane = tid & 63;
    const int w = tid >> 6;
    const int wm = (w >> 1) * 64;
    const int wn = (w & 1) * 64;
    const int m_lane = lane & 15;
    const int kq = lane >> 4;
    const int m0 = blockIdx.x * 128;
    const int n0 = blockIdx.y * 128;
    const int batch = m0 >> 11;
    const uint16_t* W = Wpt + (size_t)batch * HIDDEN * HIDDEN;
    const float* bias = bp + batch * HIDDEN;

    f32x4 acc[4][4] = {};

    for (int kb = 0; kb < HIDDEN; kb += 64) {
        for (int t = 0; t < 4; ++t) {
            int gbase = (w * 4 + t) * 64;
            int g = gbase + lane;
            int r = g >> 3;
            int c = (g & 7) ^ (r & 7);
            const uint16_t* srcA = Xq + (size_t)(m0 + r) * HIDDEN + kb + c * 8;
            __builtin_amdgcn_global_load_lds(
                (const __attribute__((address_space(1))) uint32_t*)srcA,
                (__attribute__((address_space(3))) uint32_t*)(&slds[gbase * 8]),
                16, 0, 0);
            const uint16_t* srcB = W + (size_t)(n0 + r) * HIDDEN + kb + c * 8;
            __builtin_amdgcn_global_load_lds(
                (const __attribute__((address_space(1))) uint32_t*)srcB,
                (__attribute__((address_space(3))) uint32_t*)(&slds[8192 + gbase * 8]),
                16, 0, 0);
        }
        __syncthreads();
        for (int ks = 0; ks < 2; ++ks) {
            int cbase = ks * 4 + kq;
            bf16x8 af[4], bfr[4];
            for (int i = 0; i < 4; ++i) {
                int r = wm + i * 16 + m_lane;
                int p = cbase ^ (r & 7);
                af[i] = *(const bf16x8*)(&slds[r * 64 + p * 8]);
            }
            for (int j = 0; j < 4; ++j) {
                int nr = wn + j * 16 + m_lane;
                int p = cbase ^ (nr & 7);
                bfr[j] = *(const bf16x8*)(&slds[8192 + nr * 64 + p * 8]);
            }
            for (int i = 0; i < 4; ++i)
                for (int j = 0; j < 4; ++j)
                    acc[i][j] = __builtin_amdgcn_mfma_f32_16x16x32_bf16(
                        af[i], bfr[j], acc[i][j], 0, 0, 0);
        }
        __syncthreads();
    }

    for (int j = 0; j < 4; ++j) {
        int col = n0 + wn + j * 16 + m_lane;
        float bj = bias[col];
        for (int i = 0; i < 4; ++i) {
            int rbase = m0 + wm + i * 16 + kq * 4;
            for (int rg = 0; rg < 4; ++rg)
                out[(size_t)(rbase + rg) * HIDDEN + col] = acc[i][j][rg] + bj;
        }
    }
}

// ---------------------------------------------------------------------------
extern "C" void kernel_launch(void* const* d_in, const int* in_sizes, int n_in,
                              void* d_out, int out_size, void* d_ws, size_t ws_size,
                              hipStream_t stream) {
    const float* Xq = (const float*)d_in[0];
    const float* Xk = (const float*)d_in[1];
    const float* Xv = (const float*)d_in[2];
    const float* Wq = (const float*)d_in[3];
    const float* Bq = (const float*)d_in[4];
    const float* Wk = (const float*)d_in[5];
    const float* Bk = (const float*)d_in[6];
    const float* Wv = (const float*)d_in[7];
    const float* Bv = (const float*)d_in[8];
    float* out = (float*)d_out;

    char* ws = (char*)d_ws;
    uint16_t* Xb = (uint16_t*)ws;                        // 50,331,648 B (Xq,Xk,Xv bf16)
    uint16_t* KV = (uint16_t*)(ws + 50331648);           // 33,554,432 B (K,V bf16)
    uint16_t* Wt = (uint16_t*)(ws + 83886080);           //  4,194,304 B (Wk,Wv bf16 T)
    float* P = (float*)(ws + 88080384);                  //  8,388,608 B (64bh x 8sc x 4096)
    uint16_t* Wpt = (uint16_t*)(ws + 96468992);          //  8,388,608 B (4 x W'_b)
    float* bp = (float*)(ws + 104857600);                //     16,384 B (~100 MB)

    static bool attr_done = false;
    if (!attr_done) {
        (void)hipFuncSetAttribute((const void*)projk8,
                                  hipFuncAttributeMaxDynamicSharedMemorySize, 98304);
        attr_done = true;
    }

    cvt_kernel<<<dim3(3 * 8192), 256, 0, stream>>>(Xq, Xk, Xv, Xb);
    wt_kernel<<<dim3(16, 16, 2), 256, 0, stream>>>(Wk, Wv, Wt);

    const uint16_t* Xkv = Xb + (size_t)ROWS * HIDDEN;
    // z=0 (K): 256x128 8-phase kernel (within-session A/B vs V-half).
    projk8<<<dim3(32, 8), 512, 98304, stream>>>(Xkv, Wt, Bk, KV);
    // z=1 (V): round-0-verified m97 128^2 kernel via offset pointers.
    proj_gemm<<<dim3(64, 8, 1), 256, 0, stream>>>(
        Xkv + (size_t)ROWS * HIDDEN, Wt + (size_t)HIDDEN * HIDDEN, Bv, Bv,
        KV + (size_t)ROWS * HIDDEN);

    kv_kernel<<<dim3(64, 8), 256, 0, stream>>>(KV, P);
    wprime_kernel<<<dim3(16, 16, 4), 256, 0, stream>>>(Wq, Bq, P, Wpt, bp);
    final_gemm<<<dim3(64, 8), 256, 0, stream>>>(Xb, Wpt, bp, out);
}